// Round 19
// baseline (247.890 us; speedup 1.0000x reference)
//
#include <hip/hip_runtime.h>
#include <stdint.h>

#define B_   4
#define C_   512
#define N_   4096
#define G_   32
#define CPG  16
#define EPS  1e-5f

typedef __attribute__((ext_vector_type(8))) short bf16x8;
typedef __attribute__((ext_vector_type(4))) float f32x4;
typedef __attribute__((ext_vector_type(4))) int   i32x4;

__device__ __forceinline__ unsigned short f2bf(float f){
  union { float f; uint32_t u; } v; v.f = f;
  uint32_t r = v.u + 0x7fffu + ((v.u >> 16) & 1u);
  return (unsigned short)(r >> 16);
}
__device__ __forceinline__ float bf2f(unsigned short h){
  union { uint32_t u; float f; } v; v.u = ((uint32_t)h) << 16;
  return v.f;
}

__device__ __forceinline__ void gload16(const unsigned short* g, unsigned short* l){
  __builtin_amdgcn_global_load_lds(
      (__attribute__((address_space(1))) void*)(g),
      (__attribute__((address_space(3))) void*)(l), 16, 0, 0);
}
__device__ __forceinline__ void gload16i(const signed char* g, signed char* l){
  __builtin_amdgcn_global_load_lds(
      (__attribute__((address_space(1))) void*)(g),
      (__attribute__((address_space(3))) void*)(l), 16, 0, 0);
}

// ---------------- fused weight prep: cvt x3, perm-cvt wp, concat bias -------
__global__ __launch_bounds__(256) void prep_k(const float* __restrict__ wq,
                                              const float* __restrict__ wk,
                                              const float* __restrict__ wv,
                                              const float* __restrict__ wp,
                                              const float* __restrict__ bq,
                                              const float* __restrict__ bk,
                                              const float* __restrict__ bv,
                                              unsigned short* __restrict__ qkvw,
                                              unsigned short* __restrict__ wpb,
                                              float* __restrict__ bqkv){
  const int NW = C_ * C_;
  int b = blockIdx.x;
  if (b < 1024){
    int i = (b * 256 + threadIdx.x) * 4;
    int region = i / NW;
    int off = i - region * NW;
    if (region < 3){
      const float* src = (region == 0) ? wq : (region == 1) ? wk : wv;
      float4 v = *(const float4*)(src + off);
      unsigned short* dst = qkvw + region * NW + off;
      dst[0] = f2bf(v.x); dst[1] = f2bf(v.y); dst[2] = f2bf(v.z); dst[3] = f2bf(v.w);
    } else {
      #pragma unroll
      for (int j = 0; j < 4; j++){
        int idx = off + j;
        int row = idx >> 9, col = idx & 511;
        int o = col & 63;
        int sc = (col & ~63) | (((o & 3) << 4) | (o >> 2));
        wpb[idx] = f2bf(wp[(row << 9) | sc]);
      }
    }
  } else {
    for (int i = threadIdx.x; i < 1536; i += 256)
      bqkv[i] = (i < 512) ? bq[i] : ((i < 1024) ? bk[i-512] : bv[i-1024]);
  }
}

// ---------------- groupnorm stats ----------------
__global__ __launch_bounds__(256) void gn_stats_k(const float* __restrict__ x,
                                                  float* __restrict__ stats){
  int bg = blockIdx.x;
  const float* p = x + (size_t)bg * (CPG * N_);
  float s = 0.f, ss = 0.f;
  for (int i = threadIdx.x * 4; i < CPG * N_; i += 256 * 4){
    float4 v = *(const float4*)(p + i);
    s  += v.x + v.y + v.z + v.w;
    ss += v.x*v.x + v.y*v.y + v.z*v.z + v.w*v.w;
  }
  #pragma unroll
  for (int o = 32; o >= 1; o >>= 1){ s += __shfl_xor(s, o); ss += __shfl_xor(ss, o); }
  __shared__ float sb[8];
  int w = threadIdx.x >> 6;
  if ((threadIdx.x & 63) == 0){ sb[w] = s; sb[4+w] = ss; }
  __syncthreads();
  if (threadIdx.x == 0){
    float S  = sb[0]+sb[1]+sb[2]+sb[3];
    float SS = sb[4]+sb[5]+sb[6]+sb[7];
    const float inv = 1.f / (CPG * N_);
    float mu  = S * inv;
    float var = SS * inv - mu * mu;
    stats[bg*2]   = mu;
    stats[bg*2+1] = rsqrtf(var + EPS);
  }
}

// ---------------- GN apply + transpose to t[B][N][C] bf16 ----------------
__global__ __launch_bounds__(256) void gn_apply_k(const float* __restrict__ x,
                                                  const float* __restrict__ stats,
                                                  const float* __restrict__ gw,
                                                  const float* __restrict__ gb,
                                                  unsigned short* __restrict__ t){
  int b  = blockIdx.z;
  int c0 = blockIdx.y * 64, n0 = blockIdx.x * 64;
  __shared__ float tile[64][65];
  for (int i = threadIdx.x; i < 64*64; i += 256){
    int cl = i >> 6, nl = i & 63;
    int c = c0 + cl;
    int g = c >> 4;
    float mu = stats[(b*G_+g)*2], rs = stats[(b*G_+g)*2+1];
    float v = x[((size_t)b*C_ + c)*N_ + n0 + nl];
    tile[cl][nl] = (v - mu) * rs * gw[c] + gb[c];
  }
  __syncthreads();
  for (int i = threadIdx.x; i < 64*64; i += 256){
    int nl = i >> 6, cl = i & 63;
    t[((size_t)b*N_ + n0 + nl)*C_ + c0 + cl] = f2bf(tile[cl][nl]);
  }
}

// ------- transpose+quantize v with pi-permuted token position ---------------
__global__ __launch_bounds__(256) void transpose_q8_k(const unsigned short* __restrict__ in,
                                                      signed char* __restrict__ out,
                                                      float invs){
  int r0 = blockIdx.x * 64, c0 = blockIdx.y * 64;
  size_t base_in  = (size_t)blockIdx.z * N_ * 1536;
  size_t base_out = (size_t)blockIdx.z * C_ * N_;
  __shared__ signed char tile[64][68];
  for (int i = threadIdx.x; i < 4096; i += 256){
    int rl = i >> 6, cl = i & 63;
    float v = bf2f(in[base_in + (size_t)(r0+rl)*1536 + c0 + cl]);
    int q = __float2int_rn(v * invs);
    tile[rl][cl] = (signed char)max(-127, min(127, q));
  }
  __syncthreads();
  for (int i = threadIdx.x; i < 4096; i += 256){
    int cl = i >> 6, rl = i & 63;
    int rp = ((rl & 15) << 2) | (rl >> 4);
    out[base_out + (size_t)(c0+cl)*N_ + r0 + rp] = tile[rl][cl];
  }
}

// ============ bf16 256x256 8-phase GEMM (QKV; mode 3 = fused q/k quant) =====
__global__ __launch_bounds__(512, 2) void gemm256_k(const unsigned short* __restrict__ A,
                                                    const unsigned short* __restrict__ Bm,
                                                    unsigned short* __restrict__ Cm,
                                                    int lda, int ldb, int ldc,
                                                    int kper, int zdiv, int Mb,
                                                    long long sA, long long sB,
                                                    long long sC, long long sSp,
                                                    const float* __restrict__ bias,
                                                    float scale, int mode,
                                                    signed char* __restrict__ q8p,
                                                    signed char* __restrict__ k8p,
                                                    float invqs){
  __shared__ unsigned short As[2][256*64];
  __shared__ unsigned short Bs[2][256*64];

  const int tid  = threadIdx.x;
  const int lane = tid & 63, wave = tid >> 6;
  const int wr = wave >> 2, wc = wave & 3;
  const int fr = lane & 15, kl = lane >> 4;
  const int kl8 = kl * 8;
  const int rsw = (fr & 7) << 3;

  const int gx = gridDim.x, gy = gridDim.y;
  const int nwg = gx * gy * gridDim.z;
  int bid = blockIdx.x + gx * (blockIdx.y + gy * blockIdx.z);
  if ((nwg & 7) == 0)
    bid = (bid & 7) * (nwg >> 3) + (bid >> 3);
  const int bx = bid % gx;
  const int tmp2 = bid / gx;
  const int by = tmp2 % gy;
  const int bz = tmp2 / gy;

  const int batch = bz / zdiv;
  const int sp    = bz % zdiv;
  const int koff  = sp * kper;
  const unsigned short* Ab = A  + (size_t)batch*sA + (size_t)bx * 256 * lda + koff;
  const unsigned short* Bb = Bm + (size_t)batch*sB + (size_t)by * 256 * ldb + koff;
  unsigned short*       Cb = Cm + (size_t)batch*sC + (size_t)sp*sSp;

  const int g_row = tid >> 3;
  const int g_col = ((tid & 7) * 8) ^ (((tid >> 3) & 7) << 3);
  const int lw    = wave * 512;

#define STAGE(matG, ld, ldsArr, h, kt) do {                                         \
    const unsigned short* _g0 = (matG) + (size_t)((h)*128 + g_row)*(ld)             \
                                + (size_t)(kt)*64 + g_col;                          \
    gload16(_g0,                    &ldsArr[(kt)&1][(h)*8192 + lw]);                \
    gload16(_g0 + (size_t)64*(ld),  &ldsArr[(kt)&1][(h)*8192 + 4096 + lw]);         \
  } while(0)

  f32x4 acc[8][4];
  #pragma unroll
  for (int m = 0; m < 8; m++)
    #pragma unroll
    for (int n = 0; n < 4; n++)
      acc[m][n] = (f32x4){0.f,0.f,0.f,0.f};

  const int NT = kper >> 6;

  STAGE(Ab, lda, As, 0, 0);  STAGE(Ab, lda, As, 1, 0);
  STAGE(Bb, ldb, Bs, 0, 0);  STAGE(Bb, ldb, Bs, 1, 0);
  STAGE(Bb, ldb, Bs, 0, 1);  STAGE(Bb, ldb, Bs, 1, 1);
  asm volatile("s_waitcnt vmcnt(4)" ::: "memory");
  __builtin_amdgcn_sched_barrier(0);
  __builtin_amdgcn_s_barrier();

  bf16x8 af[4][2], ag[4][2], bfr[2][2], bf2[2][2];

#define RD_A(dst, Tl, mhofs)                                                     \
    _Pragma("unroll")                                                            \
    for (int m = 0; m < 4; m++)                                                  \
      _Pragma("unroll")                                                          \
      for (int kk = 0; kk < 2; kk++)                                             \
        dst[m][kk] = *(const bf16x8*)&Tl[(wr*128 + (mhofs) + m*16 + fr)*64 + ((kk*32 + kl8) ^ rsw)];
#define RD_B(dst, Tl, nofs)                                                      \
    _Pragma("unroll")                                                            \
    for (int n = 0; n < 2; n++)                                                  \
      _Pragma("unroll")                                                          \
      for (int kk = 0; kk < 2; kk++)                                             \
        dst[n][kk] = *(const bf16x8*)&Tl[(wc*64 + (nofs) + n*16 + fr)*64 + ((kk*32 + kl8) ^ rsw)];
#define MFMA16(mbase, nbase, afr, bft)                                           \
    __builtin_amdgcn_s_setprio(1);                                               \
    _Pragma("unroll")                                                            \
    for (int m = 0; m < 4; m++)                                                  \
      _Pragma("unroll")                                                          \
      for (int n = 0; n < 2; n++)                                                \
        _Pragma("unroll")                                                        \
        for (int kk = 0; kk < 2; kk++)                                           \
          acc[(mbase)+m][(nbase)+n] = __builtin_amdgcn_mfma_f32_16x16x32_bf16(   \
              afr[m][kk], bft[n][kk], acc[(mbase)+m][(nbase)+n], 0,0,0);         \
    __builtin_amdgcn_s_setprio(0);
#define BAR_LGKM                                                                 \
    __builtin_amdgcn_s_barrier();                                                \
    asm volatile("s_waitcnt lgkmcnt(0)" ::: "memory");                           \
    __builtin_amdgcn_sched_barrier(0);

  for (int kt = 0; kt < NT; kt += 2){
    const unsigned short* __restrict__ Al0 = As[0];
    const unsigned short* __restrict__ Bl0 = Bs[0];
    const unsigned short* __restrict__ Al1 = As[1];
    const unsigned short* __restrict__ Bl1 = Bs[1];

    RD_A(af, Al0, 0)
    RD_B(bfr, Bl0, 0)
    STAGE(Ab, lda, As, 0, kt+1);
    BAR_LGKM
    MFMA16(0, 0, af, bfr)
    __builtin_amdgcn_s_barrier();

    RD_B(bf2, Bl0, 32)
    STAGE(Ab, lda, As, 1, kt+1);
    BAR_LGKM
    MFMA16(0, 2, af, bf2)
    __builtin_amdgcn_s_barrier();

    RD_A(ag, Al0, 64)
    if (kt+2 < NT) STAGE(Bb, ldb, Bs, 0, kt+2);
    BAR_LGKM
    MFMA16(4, 0, ag, bfr)
    __builtin_amdgcn_s_barrier();

    if (kt+2 < NT){
      STAGE(Bb, ldb, Bs, 1, kt+2);
      asm volatile("s_waitcnt vmcnt(4)" ::: "memory");
    } else {
      asm volatile("s_waitcnt vmcnt(0)" ::: "memory");
    }
    __builtin_amdgcn_sched_barrier(0);
    __builtin_amdgcn_s_barrier();
    __builtin_amdgcn_sched_barrier(0);
    MFMA16(4, 2, ag, bf2)
    __builtin_amdgcn_s_barrier();

    RD_A(af, Al1, 0)
    RD_B(bfr, Bl1, 0)
    if (kt+2 < NT) STAGE(Ab, lda, As, 0, kt+2);
    BAR_LGKM
    MFMA16(0, 0, af, bfr)
    __builtin_amdgcn_s_barrier();

    RD_B(bf2, Bl1, 32)
    if (kt+2 < NT) STAGE(Ab, lda, As, 1, kt+2);
    BAR_LGKM
    MFMA16(0, 2, af, bf2)
    __builtin_amdgcn_s_barrier();

    RD_A(ag, Al1, 64)
    if (kt+3 < NT) STAGE(Bb, ldb, Bs, 0, kt+3);
    BAR_LGKM
    MFMA16(4, 0, ag, bfr)
    __builtin_amdgcn_s_barrier();

    if (kt+3 < NT){
      STAGE(Bb, ldb, Bs, 1, kt+3);
      asm volatile("s_waitcnt vmcnt(4)" ::: "memory");
    } else {
      asm volatile("s_waitcnt vmcnt(0)" ::: "memory");
    }
    __builtin_amdgcn_sched_barrier(0);
    __builtin_amdgcn_s_barrier();
    __builtin_amdgcn_sched_barrier(0);
    MFMA16(4, 2, ag, bf2)
    __builtin_amdgcn_s_barrier();
  }
#undef BAR_LGKM
#undef MFMA16
#undef RD_B
#undef RD_A
#undef STAGE

  const int cr = kl * 4, cc = fr;
  if (mode == 3 && by < 4){
    signed char* dst = (by < 2) ? q8p : k8p;
    const int cb = (by & 1)*256 + wc*64 + cc*4;
    #pragma unroll
    for (int m = 0; m < 8; m++){
      #pragma unroll
      for (int r = 0; r < 4; r++){
        int gr = bx*256 + wr*128 + m*16 + cr + r;
        uint32_t pk = 0;
        #pragma unroll
        for (int n = 0; n < 4; n++){
          int gc = by*256 + wc*64 + n*16 + cc;
          float v = (acc[m][n][r] + bias[gc]) * invqs;
          int q = __float2int_rn(v);
          q = max(-127, min(127, q));
          pk |= (uint32_t)(q & 0xff) << (n*8);
        }
        *(uint32_t*)&dst[(size_t)gr*512 + cb] = pk;
      }
    }
  } else {
    #pragma unroll
    for (int m = 0; m < 8; m++){
      #pragma unroll
      for (int n = 0; n < 4; n++){
        int gc = by*256 + wc*64 + n*16 + cc;
        float bv = (mode == 1 || mode == 3) ? bias[gc] : 0.f;
        #pragma unroll
        for (int r = 0; r < 4; r++){
          int gr = bx*256 + wr*128 + m*16 + cr + r;
          Cb[(size_t)gr*ldc + gc] = f2bf((acc[m][n][r] + bv) * scale);
        }
      }
    }
  }
}

// ====== i8 128x128 GEMM, BK=128, DOUBLE-buffered LDS + counted vmcnt ======
// 64KB LDS -> 2 blocks/CU. Per K-tile: issue tile kt+1's 8 loads into buf^1,
// s_waitcnt vmcnt(8) (drains exactly tile kt's loads; kt+1 stays in flight),
// raw s_barrier, ds_read+MFMA, s_barrier. No full vmcnt(0) drain in the loop.
// Overwrite audit: buf[(kt+1)&1] last read at iter kt-1, reads done before
// its closing barrier; STG issued after that barrier -> race-free.
// MODE 2 (QK): S8 packed at pi-permuted cols + integer row sums -> lpart.
// MODE 0 (PV): packed 4xbf16, val = acc*c1*linv[row].
template<int KPER, int MODE>
__global__ __launch_bounds__(256, 2) void gemm128i_db_k(const signed char* __restrict__ A,
                                                        const signed char* __restrict__ Bm,
                                                        void* __restrict__ Cv,
                                                        int Mb,
                                                        long long sA, long long sB, long long sC,
                                                        float c1, float c2,
                                                        float* __restrict__ lpart, int lrows,
                                                        const float* __restrict__ linv){
  __shared__ signed char As[2][128*128];
  __shared__ signed char Bs[2][128*128];

  const int tid  = threadIdx.x;
  const int lane = tid & 63, wave = tid >> 6;
  const int wr = wave >> 1, wc = wave & 1;
  const int fr = lane & 15, kl = lane >> 4;
  const int rs = fr & 7;
  const int ldc = (MODE == 2) ? N_ : C_;

  const int gx = gridDim.x, gy = gridDim.y;
  const int nwg = gx * gy * gridDim.z;
  int bid = blockIdx.x + gx * (blockIdx.y + gy * blockIdx.z);
  if ((nwg & 7) == 0)
    bid = (bid & 7) * (nwg >> 3) + (bid >> 3);
  const int bx = bid % gx;
  const int tmp2 = bid / gx;
  const int by = tmp2 % gy;
  const int batch = tmp2 / gy;

  const signed char* Ab = A  + (size_t)batch*sA + (size_t)bx * 128 * KPER;
  const signed char* Bb = Bm + (size_t)batch*sB + (size_t)by * 128 * KPER;

  const int srow = tid >> 3;                                 // 0..31 (+ p*32)
  const int gcol = ((tid & 7) ^ ((tid >> 3) & 7)) * 16;
  const signed char* gA = Ab + (size_t)srow * KPER + gcol;
  const signed char* gB = Bb + (size_t)srow * KPER + gcol;
  const int lofs = srow * 128 + (tid & 7) * 16;              // linear dest in buf

#define STG(kt, buf) do {                                                        \
    _Pragma("unroll")                                                            \
    for (int p = 0; p < 4; p++){                                                 \
      gload16i(gA + (size_t)(p*32)*KPER + (size_t)(kt)*128, &As[buf][lofs + p*4096]); \
      gload16i(gB + (size_t)(p*32)*KPER + (size_t)(kt)*128, &Bs[buf][lofs + p*4096]); \
    } } while(0)

  i32x4 acc[4][4];
  #pragma unroll
  for (int m = 0; m < 4; m++)
    #pragma unroll
    for (int n = 0; n < 4; n++)
      acc[m][n] = (i32x4){0,0,0,0};

  constexpr int NT = KPER >> 7;

  STG(0, 0);                                  // prologue: tile0 -> buf0 (8 loads)

  #pragma unroll (NT <= 4 ? NT : 2)
  for (int kt = 0; kt < NT; kt++){
    const int buf = kt & 1;
    if (kt+1 < NT){
      STG(kt+1, buf^1);                       // outstanding: kt's 8 + kt+1's 8
      asm volatile("s_waitcnt vmcnt(8)" ::: "memory");   // drain kt's only
    } else {
      asm volatile("s_waitcnt vmcnt(0)" ::: "memory");
    }
    __builtin_amdgcn_sched_barrier(0);
    __builtin_amdgcn_s_barrier();             // tile kt resident for all waves
    const signed char* __restrict__ Al = As[buf];
    const signed char* __restrict__ Bl = Bs[buf];
    i32x4 af[4][2], bf[4][2];
    #pragma unroll
    for (int m = 0; m < 4; m++)
      #pragma unroll
      for (int kk = 0; kk < 2; kk++)
        af[m][kk] = *(const i32x4*)&Al[(wr*64 + m*16 + fr)*128 + (((kk*4 + kl) ^ rs) << 4)];
    #pragma unroll
    for (int n = 0; n < 4; n++)
      #pragma unroll
      for (int kk = 0; kk < 2; kk++)
        bf[n][kk] = *(const i32x4*)&Bl[(wc*64 + n*16 + fr)*128 + (((kk*4 + kl) ^ rs) << 4)];
    __builtin_amdgcn_s_setprio(1);
    #pragma unroll
    for (int m = 0; m < 4; m++)
      #pragma unroll
      for (int n = 0; n < 4; n++)
        #pragma unroll
        for (int kk = 0; kk < 2; kk++)
          acc[m][n] = __builtin_amdgcn_mfma_i32_16x16x64_i8(af[m][kk], bf[n][kk], acc[m][n], 0,0,0);
    __builtin_amdgcn_s_setprio(0);
    __builtin_amdgcn_s_barrier();             // reads done before buf overwrite
  }
#undef STG

  const int cr = kl * 4, cc = fr;
  if (MODE == 2){
    signed char* Cb = (signed char*)Cv + (size_t)batch*sC;
    const int cb = by*128 + wc*64 + cc*4;      // pi-permuted packed col base
    const int slice = by*2 + wc;
    #pragma unroll
    for (int m = 0; m < 4; m++){
      #pragma unroll
      for (int r = 0; r < 4; r++){
        int gr = bx*128 + wr*64 + m*16 + cr + r;
        uint32_t pk = 0;
        int ip = 0;
        #pragma unroll
        for (int n = 0; n < 4; n++){
          float arg = (float)acc[m][n][r] * c1 + c2;
          arg = fminf(arg, 6.99f);
          float p = exp2f(arg);
          int pq = (int)(p + 0.5f);
          pk |= (uint32_t)pq << (n*8);
          ip += pq;
        }
        *(uint32_t*)&Cb[(size_t)gr*ldc + cb] = pk;
        float v = (float)ip;
        v += __shfl_xor(v, 1); v += __shfl_xor(v, 2);
        v += __shfl_xor(v, 4); v += __shfl_xor(v, 8);
        if (cc == 0)
          lpart[(size_t)slice * lrows + batch*Mb + gr] = v;
      }
    }
  } else {
    unsigned short* Cb = (unsigned short*)Cv + (size_t)batch*sC;
    const int cb = by*128 + wc*64 + cc*4;      // packed col base (shorts)
    #pragma unroll
    for (int m = 0; m < 4; m++){
      #pragma unroll
      for (int r = 0; r < 4; r++){
        int gr = bx*128 + wr*64 + m*16 + cr + r;
        float li = linv[batch*Mb + gr] * c1;
        unsigned short w0 = f2bf((float)acc[m][0][r] * li);
        unsigned short w1 = f2bf((float)acc[m][1][r] * li);
        unsigned short w2 = f2bf((float)acc[m][2][r] * li);
        unsigned short w3 = f2bf((float)acc[m][3][r] * li);
        uint2 pk;
        pk.x = (uint32_t)w0 | ((uint32_t)w1 << 16);
        pk.y = (uint32_t)w2 | ((uint32_t)w3 << 16);
        *(uint2*)&Cb[(size_t)gr*ldc + cb] = pk;
      }
    }
  }
}

// ====== 128x128 GEMM + bias + RESIDUAL, f32 out[b][C][N] (proj fused) ======
__global__ __launch_bounds__(256, 2) void gemm_projres_k(const unsigned short* __restrict__ A,
                                                         const unsigned short* __restrict__ Bm,
                                                         const float* __restrict__ bias,
                                                         const float* __restrict__ x,
                                                         float* __restrict__ out){
  __shared__ unsigned short As[128*32];
  __shared__ unsigned short Bs[128*32];
  __shared__ float xscr[4][16*68];

  const int tid  = threadIdx.x;
  const int lane = tid & 63, wave = tid >> 6;
  const int wr = wave >> 1, wc = wave & 1;
  const int lda = C_, ldb = C_, K = C_;

  const int gx = gridDim.x, gy = gridDim.y;
  const int nwg = gx * gy;
  int bid = blockIdx.x + gx * blockIdx.y;
  if ((nwg & 7) == 0)
    bid = (bid & 7) * (nwg >> 3) + (bid >> 3);
  const int bx = bid % gx;
  const int by = bid / gx;

  const unsigned short* Ab = A  + (size_t)bx * 128 * lda;
  const unsigned short* Bb = Bm + (size_t)by * 128 * ldb;

  f32x4 acc[4][4];
  #pragma unroll
  for (int i = 0; i < 4; i++)
    #pragma unroll
    for (int j = 0; j < 4; j++)
      acc[i][j] = (f32x4){0.f, 0.f, 0.f, 0.f};

  const int ch0  = wave * 2;
  const int srow = ch0 * 16 + (lane >> 2);
  const int scol = (lane & 3) * 8;
  const unsigned short* gA0 = Ab + (size_t)srow * lda + scol;
  const unsigned short* gA1 = gA0 + (size_t)16 * lda;
  const unsigned short* gB0 = Bb + (size_t)srow * ldb + scol;
  const unsigned short* gB1 = gB0 + (size_t)16 * ldb;
  unsigned short* lA0 = &As[ch0 * 512];
  unsigned short* lA1 = &As[ch0 * 512 + 512];
  unsigned short* lB0 = &Bs[ch0 * 512];
  unsigned short* lB1 = &Bs[ch0 * 512 + 512];

  const int fr = lane & 15;
  const int fk = (lane >> 4) * 8;

  for (int k0 = 0; k0 < K; k0 += 32){
    gload16(gA0 + k0, lA0);
    gload16(gA1 + k0, lA1);
    gload16(gB0 + k0, lB0);
    gload16(gB1 + k0, lB1);
    __syncthreads();
    bf16x8 af[4], bfr[4];
    #pragma unroll
    for (int i = 0; i < 4; i++) af[i]  = *(const bf16x8*)&As[(wr*64 + i*16 + fr)*32 + fk];
    #pragma unroll
    for (int j = 0; j < 4; j++) bfr[j] = *(const bf16x8*)&Bs[(wc*64 + j*16 + fr)*32 + fk];
    #pragma unroll
    for (int i = 0; i < 4; i++)
      #pragma unroll
      for (int j = 0; j < 4; j++)
        acc[i][j] = __builtin_amdgcn_mfma_f32_16x16x32_bf16(af[i], bfr[j], acc[i][j], 0, 0, 0);
    __syncthreads();
  }

  const int cr = (lane >> 4) * 4, cc = lane & 15;
  float* scr = xscr[wave];
  const int b   = bx >> 5;
  const int n0b = (bx & 31) * 128 + wr * 64;
  const int colrd = lane >> 2;
  const int nseg  = (lane & 3) * 16;
  #pragma unroll
  for (int p = 0; p < 4; p++){
    float bv = bias[by*128 + wc*64 + p*16 + cc];
    #pragma unroll
    for (int i = 0; i < 4; i++)
      #pragma unroll
      for (int r = 0; r < 4; r++)
        scr[cc*68 + i*16 + cr + r] = acc[i][p][r] + bv;
    int col = by*128 + wc*64 + p*16 + colrd;
    size_t base = ((size_t)b*C_ + col)*N_ + n0b + nseg;
    const float* sr = &scr[colrd*68 + nseg];
    #pragma unroll
    for (int e = 0; e < 16; e += 4){
      float4 xv = *(const float4*)(x + base + e);
      float4 sv = *(const float4*)(sr + e);
      float4 ov;
      ov.x = xv.x + sv.x; ov.y = xv.y + sv.y;
      ov.z = xv.z + sv.z; ov.w = xv.w + sv.w;
      *(float4*)(out + base + e) = ov;
    }
    __builtin_amdgcn_s_barrier();
  }
}

// ---------------- reduce row-sum slices -> 1/l ----------------
__global__ __launch_bounds__(256) void lreduce_k(const float* __restrict__ lpart,
                                                 float* __restrict__ linv,
                                                 int slices, int rows){
  int r = blockIdx.x * 256 + threadIdx.x;
  if (r < rows){
    float s = 0.f;
    for (int i = 0; i < slices; i++) s += lpart[(size_t)i*rows + r];
    linv[r] = 1.f / fmaxf(s, 1.f);
  }
}

extern "C" void kernel_launch(void* const* d_in, const int* in_sizes, int n_in,
                              void* d_out, int out_size, void* d_ws, size_t ws_size,
                              hipStream_t stream){
  const float* x   = (const float*)d_in[0];
  const float* gnw = (const float*)d_in[1];
  const float* gnb = (const float*)d_in[2];
  const float* wq  = (const float*)d_in[3];
  const float* bq  = (const float*)d_in[4];
  const float* wk  = (const float*)d_in[5];
  const float* bk  = (const float*)d_in[6];
  const float* wv  = (const float*)d_in[7];
  const float* bv  = (const float*)d_in[8];
  const float* wp  = (const float*)d_in[9];
  const float* bp  = (const float*)d_in[10];
  float* out = (float*)d_out;

  char* ws = (char*)d_ws;
  const int  Mtok = B_ * N_;                      // 16384
  const size_t TSZ   = (size_t)Mtok * C_ * 2;     // 16 MB
  const size_t QKVSZ = (size_t)Mtok * 1536 * 2;   // 48 MB
  const size_t S8SZ  = (size_t)B_ * N_ * N_;      // 64 MB (i8)
  const size_t Q8SZ  = (size_t)Mtok * C_;         // 8 MB (i8)
  size_t off = 0;
  float*          stats = (float*)ws;               off += 4096;
  unsigned short* qkvw = (unsigned short*)(ws+off); off += (size_t)1536 * C_ * 2;
  unsigned short* wpb  = (unsigned short*)(ws+off); off += (size_t)C_ * C_ * 2;
  float*          bqkv = (float*)(ws+off);          off += 1536 * 4 + 2048;
  unsigned short* t    = (unsigned short*)(ws+off); off += TSZ;    // later: o
  unsigned short* qkv  = (unsigned short*)(ws+off); off += QKVSZ;
  signed char*    S8   = (signed char*)(ws+off);    off += S8SZ;
  float*          lpart = (float*)(ws+off);         off += (size_t)64 * Mtok * 4;
  float*          linv  = (float*)(ws+off);         off += (size_t)Mtok * 4;
  signed char*    q8   = (signed char*)(ws+off);    off += Q8SZ;
  signed char*    k8   = (signed char*)(ws+off);    off += Q8SZ;
  signed char*    vt8  = (signed char*)(ws+off);    off += Q8SZ;

  unsigned short* o = t;                            // t dead after QKV GEMM

  const float QS    = 6.f / 127.f;
  const float INVQS = 127.f / 6.f;
  const float qkscale = QS * QS * 0.044194173824159216f;
  const float qk_c1 = qkscale * 1.4426950408889634f;     // log2-space scale
  const float qk_c2 = -0.22478961f;                      // log2(127/e^5)

  prep_k<<<1025, 256, 0, stream>>>(wq, wk, wv, wp, bq, bk, bv, qkvw, wpb, bqkv);

  gn_stats_k<<<B_ * G_, 256, 0, stream>>>(x, stats);
  gn_apply_k<<<dim3(N_/64, C_/64, B_), 256, 0, stream>>>(x, stats, gnw, gnb, t);

  // QKV: mode 3 — by<4 writes packed i8 q8/k8 (pi-permuted channels), by>=4 bf16 v
  gemm256_k<<<dim3(Mtok/256, 1536/256, 1), 512, 0, stream>>>(
      t, qkvw, qkv, C_, C_, 1536, C_, 1, Mtok, 0,0,0,0, bqkv, 1.f, 3, q8, k8, INVQS);

  // v -> vt8[b][d][pi(n)] i8
  transpose_q8_k<<<dim3(N_/64, C_/64, B_), 256, 0, stream>>>(qkv + 1024, vt8, INVQS);

  const long long sQ8 = (long long)N_ * C_;
  const long long sNN = (long long)N_ * N_;
  const long long sNC = (long long)N_ * C_;

  // QK (i8 128^2 dbuf, KPER=512): S8 packed; row sums -> lpart (64 slices)
  gemm128i_db_k<512, 2><<<dim3(N_/128, N_/128, B_), 256, 0, stream>>>(
      q8, k8, S8, N_, sQ8, sQ8, sNN, qk_c1, qk_c2, lpart, Mtok, nullptr);

  lreduce_k<<<Mtok/256, 256, 0, stream>>>(lpart, linv, 64, Mtok);

  // PV (i8 128^2 dbuf, KPER=4096): o = (S8 x Vt8) * QS * linv[row]
  gemm128i_db_k<4096, 0><<<dim3(N_/128, C_/128, B_), 256, 0, stream>>>(
      S8, vt8, o, N_, sNN, sQ8, sNC, QS, 0.f, nullptr, 0, linv);

  // out = x + o wp^T + bp   (residual fused into proj epilogue, f32 out)
  gemm_projres_k<<<dim3(Mtok/128, C_/128), 256, 0, stream>>>(o, wpb, bp, x, out);
}

// Round 20
// 236.056 us; speedup vs baseline: 1.0501x; 1.0501x over previous
//
#include <hip/hip_runtime.h>
#include <stdint.h>

#define B_   4
#define C_   512
#define N_   4096
#define G_   32
#define CPG  16
#define EPS  1e-5f

typedef __attribute__((ext_vector_type(8))) short bf16x8;
typedef __attribute__((ext_vector_type(4))) float f32x4;
typedef __attribute__((ext_vector_type(4))) int   i32x4;

__device__ __forceinline__ unsigned short f2bf(float f){
  union { float f; uint32_t u; } v; v.f = f;
  uint32_t r = v.u + 0x7fffu + ((v.u >> 16) & 1u);
  return (unsigned short)(r >> 16);
}
__device__ __forceinline__ float bf2f(unsigned short h){
  union { uint32_t u; float f; } v; v.u = ((uint32_t)h) << 16;
  return v.f;
}

__device__ __forceinline__ void gload16(const unsigned short* g, unsigned short* l){
  __builtin_amdgcn_global_load_lds(
      (__attribute__((address_space(1))) void*)(g),
      (__attribute__((address_space(3))) void*)(l), 16, 0, 0);
}
__device__ __forceinline__ void gload16i(const signed char* g, signed char* l){
  __builtin_amdgcn_global_load_lds(
      (__attribute__((address_space(1))) void*)(g),
      (__attribute__((address_space(3))) void*)(l), 16, 0, 0);
}

// ---------------- fused weight prep: cvt x3, perm-cvt wp, concat bias -------
__global__ __launch_bounds__(256) void prep_k(const float* __restrict__ wq,
                                              const float* __restrict__ wk,
                                              const float* __restrict__ wv,
                                              const float* __restrict__ wp,
                                              const float* __restrict__ bq,
                                              const float* __restrict__ bk,
                                              const float* __restrict__ bv,
                                              unsigned short* __restrict__ qkvw,
                                              unsigned short* __restrict__ wpb,
                                              float* __restrict__ bqkv){
  const int NW = C_ * C_;
  int b = blockIdx.x;
  if (b < 1024){
    int i = (b * 256 + threadIdx.x) * 4;         // [0, 4*NW)
    int region = i / NW;
    int off = i - region * NW;
    if (region < 3){
      const float* src = (region == 0) ? wq : (region == 1) ? wk : wv;
      float4 v = *(const float4*)(src + off);
      unsigned short* dst = qkvw + region * NW + off;
      dst[0] = f2bf(v.x); dst[1] = f2bf(v.y); dst[2] = f2bf(v.z); dst[3] = f2bf(v.w);
    } else {
      #pragma unroll
      for (int j = 0; j < 4; j++){
        int idx = off + j;
        int row = idx >> 9, col = idx & 511;
        int o = col & 63;
        int sc = (col & ~63) | (((o & 3) << 4) | (o >> 2));
        wpb[idx] = f2bf(wp[(row << 9) | sc]);
      }
    }
  } else {
    for (int i = threadIdx.x; i < 1536; i += 256)
      bqkv[i] = (i < 512) ? bq[i] : ((i < 1024) ? bk[i-512] : bv[i-1024]);
  }
}

// ---------------- groupnorm stats ----------------
__global__ __launch_bounds__(256) void gn_stats_k(const float* __restrict__ x,
                                                  float* __restrict__ stats){
  int bg = blockIdx.x;
  const float* p = x + (size_t)bg * (CPG * N_);
  float s = 0.f, ss = 0.f;
  for (int i = threadIdx.x * 4; i < CPG * N_; i += 256 * 4){
    float4 v = *(const float4*)(p + i);
    s  += v.x + v.y + v.z + v.w;
    ss += v.x*v.x + v.y*v.y + v.z*v.z + v.w*v.w;
  }
  #pragma unroll
  for (int o = 32; o >= 1; o >>= 1){ s += __shfl_xor(s, o); ss += __shfl_xor(ss, o); }
  __shared__ float sb[8];
  int w = threadIdx.x >> 6;
  if ((threadIdx.x & 63) == 0){ sb[w] = s; sb[4+w] = ss; }
  __syncthreads();
  if (threadIdx.x == 0){
    float S  = sb[0]+sb[1]+sb[2]+sb[3];
    float SS = sb[4]+sb[5]+sb[6]+sb[7];
    const float inv = 1.f / (CPG * N_);
    float mu  = S * inv;
    float var = SS * inv - mu * mu;
    stats[bg*2]   = mu;
    stats[bg*2+1] = rsqrtf(var + EPS);
  }
}

// ---------------- GN apply + transpose to t[B][N][C] bf16 ----------------
__global__ __launch_bounds__(256) void gn_apply_k(const float* __restrict__ x,
                                                  const float* __restrict__ stats,
                                                  const float* __restrict__ gw,
                                                  const float* __restrict__ gb,
                                                  unsigned short* __restrict__ t){
  int b  = blockIdx.z;
  int c0 = blockIdx.y * 64, n0 = blockIdx.x * 64;
  __shared__ float tile[64][65];
  for (int i = threadIdx.x; i < 64*64; i += 256){
    int cl = i >> 6, nl = i & 63;
    int c = c0 + cl;
    int g = c >> 4;
    float mu = stats[(b*G_+g)*2], rs = stats[(b*G_+g)*2+1];
    float v = x[((size_t)b*C_ + c)*N_ + n0 + nl];
    tile[cl][nl] = (v - mu) * rs * gw[c] + gb[c];
  }
  __syncthreads();
  for (int i = threadIdx.x; i < 64*64; i += 256){
    int nl = i >> 6, cl = i & 63;
    t[((size_t)b*N_ + n0 + nl)*C_ + c0 + cl] = f2bf(tile[cl][nl]);
  }
}

// ------- transpose+quantize v with pi-permuted token position ---------------
__global__ __launch_bounds__(256) void transpose_q8_k(const unsigned short* __restrict__ in,
                                                      signed char* __restrict__ out,
                                                      float invs){
  int r0 = blockIdx.x * 64, c0 = blockIdx.y * 64;
  size_t base_in  = (size_t)blockIdx.z * N_ * 1536;
  size_t base_out = (size_t)blockIdx.z * C_ * N_;
  __shared__ signed char tile[64][68];
  for (int i = threadIdx.x; i < 4096; i += 256){
    int rl = i >> 6, cl = i & 63;
    float v = bf2f(in[base_in + (size_t)(r0+rl)*1536 + c0 + cl]);
    int q = __float2int_rn(v * invs);
    tile[rl][cl] = (signed char)max(-127, min(127, q));
  }
  __syncthreads();
  for (int i = threadIdx.x; i < 4096; i += 256){
    int cl = i >> 6, rl = i & 63;
    int rp = ((rl & 15) << 2) | (rl >> 4);
    out[base_out + (size_t)(c0+cl)*N_ + r0 + rp] = tile[rl][cl];
  }
}

// ============ bf16 256x256 8-phase GEMM (QKV; mode 3 = fused q/k quant) =====
__global__ __launch_bounds__(512, 2) void gemm256_k(const unsigned short* __restrict__ A,
                                                    const unsigned short* __restrict__ Bm,
                                                    unsigned short* __restrict__ Cm,
                                                    int lda, int ldb, int ldc,
                                                    int kper, int zdiv, int Mb,
                                                    long long sA, long long sB,
                                                    long long sC, long long sSp,
                                                    const float* __restrict__ bias,
                                                    float scale, int mode,
                                                    signed char* __restrict__ q8p,
                                                    signed char* __restrict__ k8p,
                                                    float invqs){
  __shared__ unsigned short As[2][256*64];
  __shared__ unsigned short Bs[2][256*64];

  const int tid  = threadIdx.x;
  const int lane = tid & 63, wave = tid >> 6;
  const int wr = wave >> 2, wc = wave & 3;
  const int fr = lane & 15, kl = lane >> 4;
  const int kl8 = kl * 8;
  const int rsw = (fr & 7) << 3;

  const int gx = gridDim.x, gy = gridDim.y;
  const int nwg = gx * gy * gridDim.z;
  int bid = blockIdx.x + gx * (blockIdx.y + gy * blockIdx.z);
  if ((nwg & 7) == 0)
    bid = (bid & 7) * (nwg >> 3) + (bid >> 3);
  const int bx = bid % gx;
  const int tmp2 = bid / gx;
  const int by = tmp2 % gy;
  const int bz = tmp2 / gy;

  const int batch = bz / zdiv;
  const int sp    = bz % zdiv;
  const int koff  = sp * kper;
  const unsigned short* Ab = A  + (size_t)batch*sA + (size_t)bx * 256 * lda + koff;
  const unsigned short* Bb = Bm + (size_t)batch*sB + (size_t)by * 256 * ldb + koff;
  unsigned short*       Cb = Cm + (size_t)batch*sC + (size_t)sp*sSp;

  const int g_row = tid >> 3;
  const int g_col = ((tid & 7) * 8) ^ (((tid >> 3) & 7) << 3);
  const int lw    = wave * 512;

#define STAGE(matG, ld, ldsArr, h, kt) do {                                         \
    const unsigned short* _g0 = (matG) + (size_t)((h)*128 + g_row)*(ld)             \
                                + (size_t)(kt)*64 + g_col;                          \
    gload16(_g0,                    &ldsArr[(kt)&1][(h)*8192 + lw]);                \
    gload16(_g0 + (size_t)64*(ld),  &ldsArr[(kt)&1][(h)*8192 + 4096 + lw]);         \
  } while(0)

  f32x4 acc[8][4];
  #pragma unroll
  for (int m = 0; m < 8; m++)
    #pragma unroll
    for (int n = 0; n < 4; n++)
      acc[m][n] = (f32x4){0.f,0.f,0.f,0.f};

  const int NT = kper >> 6;

  STAGE(Ab, lda, As, 0, 0);  STAGE(Ab, lda, As, 1, 0);
  STAGE(Bb, ldb, Bs, 0, 0);  STAGE(Bb, ldb, Bs, 1, 0);
  STAGE(Bb, ldb, Bs, 0, 1);  STAGE(Bb, ldb, Bs, 1, 1);
  asm volatile("s_waitcnt vmcnt(4)" ::: "memory");
  __builtin_amdgcn_sched_barrier(0);
  __builtin_amdgcn_s_barrier();

  bf16x8 af[4][2], ag[4][2], bfr[2][2], bf2[2][2];

#define RD_A(dst, Tl, mhofs)                                                     \
    _Pragma("unroll")                                                            \
    for (int m = 0; m < 4; m++)                                                  \
      _Pragma("unroll")                                                          \
      for (int kk = 0; kk < 2; kk++)                                             \
        dst[m][kk] = *(const bf16x8*)&Tl[(wr*128 + (mhofs) + m*16 + fr)*64 + ((kk*32 + kl8) ^ rsw)];
#define RD_B(dst, Tl, nofs)                                                      \
    _Pragma("unroll")                                                            \
    for (int n = 0; n < 2; n++)                                                  \
      _Pragma("unroll")                                                          \
      for (int kk = 0; kk < 2; kk++)                                             \
        dst[n][kk] = *(const bf16x8*)&Tl[(wc*64 + (nofs) + n*16 + fr)*64 + ((kk*32 + kl8) ^ rsw)];
#define MFMA16(mbase, nbase, afr, bft)                                           \
    __builtin_amdgcn_s_setprio(1);                                               \
    _Pragma("unroll")                                                            \
    for (int m = 0; m < 4; m++)                                                  \
      _Pragma("unroll")                                                          \
      for (int n = 0; n < 2; n++)                                                \
        _Pragma("unroll")                                                        \
        for (int kk = 0; kk < 2; kk++)                                           \
          acc[(mbase)+m][(nbase)+n] = __builtin_amdgcn_mfma_f32_16x16x32_bf16(   \
              afr[m][kk], bft[n][kk], acc[(mbase)+m][(nbase)+n], 0,0,0);         \
    __builtin_amdgcn_s_setprio(0);
#define BAR_LGKM                                                                 \
    __builtin_amdgcn_s_barrier();                                                \
    asm volatile("s_waitcnt lgkmcnt(0)" ::: "memory");                           \
    __builtin_amdgcn_sched_barrier(0);

  for (int kt = 0; kt < NT; kt += 2){
    const unsigned short* __restrict__ Al0 = As[0];
    const unsigned short* __restrict__ Bl0 = Bs[0];
    const unsigned short* __restrict__ Al1 = As[1];
    const unsigned short* __restrict__ Bl1 = Bs[1];

    RD_A(af, Al0, 0)
    RD_B(bfr, Bl0, 0)
    STAGE(Ab, lda, As, 0, kt+1);
    BAR_LGKM
    MFMA16(0, 0, af, bfr)
    __builtin_amdgcn_s_barrier();

    RD_B(bf2, Bl0, 32)
    STAGE(Ab, lda, As, 1, kt+1);
    BAR_LGKM
    MFMA16(0, 2, af, bf2)
    __builtin_amdgcn_s_barrier();

    RD_A(ag, Al0, 64)
    if (kt+2 < NT) STAGE(Bb, ldb, Bs, 0, kt+2);
    BAR_LGKM
    MFMA16(4, 0, ag, bfr)
    __builtin_amdgcn_s_barrier();

    if (kt+2 < NT){
      STAGE(Bb, ldb, Bs, 1, kt+2);
      asm volatile("s_waitcnt vmcnt(4)" ::: "memory");
    } else {
      asm volatile("s_waitcnt vmcnt(0)" ::: "memory");
    }
    __builtin_amdgcn_sched_barrier(0);
    __builtin_amdgcn_s_barrier();
    __builtin_amdgcn_sched_barrier(0);
    MFMA16(4, 2, ag, bf2)
    __builtin_amdgcn_s_barrier();

    RD_A(af, Al1, 0)
    RD_B(bfr, Bl1, 0)
    if (kt+2 < NT) STAGE(Ab, lda, As, 0, kt+2);
    BAR_LGKM
    MFMA16(0, 0, af, bfr)
    __builtin_amdgcn_s_barrier();

    RD_B(bf2, Bl1, 32)
    if (kt+2 < NT) STAGE(Ab, lda, As, 1, kt+2);
    BAR_LGKM
    MFMA16(0, 2, af, bf2)
    __builtin_amdgcn_s_barrier();

    RD_A(ag, Al1, 64)
    if (kt+3 < NT) STAGE(Bb, ldb, Bs, 0, kt+3);
    BAR_LGKM
    MFMA16(4, 0, ag, bfr)
    __builtin_amdgcn_s_barrier();

    if (kt+3 < NT){
      STAGE(Bb, ldb, Bs, 1, kt+3);
      asm volatile("s_waitcnt vmcnt(4)" ::: "memory");
    } else {
      asm volatile("s_waitcnt vmcnt(0)" ::: "memory");
    }
    __builtin_amdgcn_sched_barrier(0);
    __builtin_amdgcn_s_barrier();
    __builtin_amdgcn_sched_barrier(0);
    MFMA16(4, 2, ag, bf2)
    __builtin_amdgcn_s_barrier();
  }
#undef BAR_LGKM
#undef MFMA16
#undef RD_B
#undef RD_A
#undef STAGE

  const int cr = kl * 4, cc = fr;
  if (mode == 3 && by < 4){
    signed char* dst = (by < 2) ? q8p : k8p;
    const int cb = (by & 1)*256 + wc*64 + cc*4;
    #pragma unroll
    for (int m = 0; m < 8; m++){
      #pragma unroll
      for (int r = 0; r < 4; r++){
        int gr = bx*256 + wr*128 + m*16 + cr + r;
        uint32_t pk = 0;
        #pragma unroll
        for (int n = 0; n < 4; n++){
          int gc = by*256 + wc*64 + n*16 + cc;
          float v = (acc[m][n][r] + bias[gc]) * invqs;
          int q = __float2int_rn(v);
          q = max(-127, min(127, q));
          pk |= (uint32_t)(q & 0xff) << (n*8);
        }
        *(uint32_t*)&dst[(size_t)gr*512 + cb] = pk;
      }
    }
  } else {
    #pragma unroll
    for (int m = 0; m < 8; m++){
      #pragma unroll
      for (int n = 0; n < 4; n++){
        int gc = by*256 + wc*64 + n*16 + cc;
        float bv = (mode == 1 || mode == 3) ? bias[gc] : 0.f;
        #pragma unroll
        for (int r = 0; r < 4; r++){
          int gr = bx*256 + wr*128 + m*16 + cr + r;
          Cb[(size_t)gr*ldc + gc] = f2bf((acc[m][n][r] + bv) * scale);
        }
      }
    }
  }
}

// ============ i8 QK GEMM: 256x128 tile, BK=128 — compile-time K ============
template<int KPER>
__global__ __launch_bounds__(512, 4) void qk256i_k(const signed char* __restrict__ A,
                                                   const signed char* __restrict__ Bm,
                                                   signed char* __restrict__ Cv,
                                                   int Mb,
                                                   long long sA, long long sB, long long sC,
                                                   float c1, float c2,
                                                   float* __restrict__ lpart, int lrows){
  __shared__ signed char As[256*128];
  __shared__ signed char Bs[128*128];

  const int tid  = threadIdx.x;
  const int lane = tid & 63, wave = tid >> 6;
  const int wr = wave >> 1, wc = wave & 1;
  const int fr = lane & 15, kl = lane >> 4;
  const int rs = fr & 7;
  const int ldc = N_;

  const int gx = gridDim.x, gy = gridDim.y;
  const int nwg = gx * gy * gridDim.z;
  int bid = blockIdx.x + gx * (blockIdx.y + gy * blockIdx.z);
  if ((nwg & 7) == 0)
    bid = (bid & 7) * (nwg >> 3) + (bid >> 3);
  const int bx = bid % gx;
  const int tmp2 = bid / gx;
  const int by = tmp2 % gy;
  const int batch = tmp2 / gy;

  const signed char* Ab = A  + (size_t)batch*sA + (size_t)bx * 256 * KPER;
  const signed char* Bb = Bm + (size_t)batch*sB + (size_t)by * 128 * KPER;

  const int srow = tid >> 3;                                 // 0..63
  const int gcol = ((tid & 7) ^ ((tid >> 3) & 7)) * 16;
  const signed char* gA = Ab + (size_t)srow * KPER + gcol;
  const signed char* gB = Bb + (size_t)srow * KPER + gcol;
  signed char* lA = &As[tid * 16];
  signed char* lB = &Bs[tid * 16];

  i32x4 acc[4][4];
  #pragma unroll
  for (int m = 0; m < 4; m++)
    #pragma unroll
    for (int n = 0; n < 4; n++)
      acc[m][n] = (i32x4){0,0,0,0};

  constexpr int NT = KPER >> 7;

  #pragma unroll
  for (int kt = 0; kt < NT; kt++){
    #pragma unroll
    for (int p = 0; p < 4; p++)
      gload16i(gA + (size_t)(p*64)*KPER + kt*128, lA + p*8192);
    #pragma unroll
    for (int p = 0; p < 2; p++)
      gload16i(gB + (size_t)(p*64)*KPER + kt*128, lB + p*8192);
    __syncthreads();
    i32x4 af[4][2], bf[4][2];
    #pragma unroll
    for (int m = 0; m < 4; m++)
      #pragma unroll
      for (int kk = 0; kk < 2; kk++)
        af[m][kk] = *(const i32x4*)&As[(wr*64 + m*16 + fr)*128 + (((kk*4 + kl) ^ rs) << 4)];
    #pragma unroll
    for (int n = 0; n < 4; n++)
      #pragma unroll
      for (int kk = 0; kk < 2; kk++)
        bf[n][kk] = *(const i32x4*)&Bs[(wc*64 + n*16 + fr)*128 + (((kk*4 + kl) ^ rs) << 4)];
    #pragma unroll
    for (int m = 0; m < 4; m++)
      #pragma unroll
      for (int n = 0; n < 4; n++)
        #pragma unroll
        for (int kk = 0; kk < 2; kk++)
          acc[m][n] = __builtin_amdgcn_mfma_i32_16x16x64_i8(af[m][kk], bf[n][kk], acc[m][n], 0,0,0);
    __syncthreads();
  }

  const int cr = kl * 4, cc = fr;
  signed char* Cb = Cv + (size_t)batch*sC;
  const int cb = by*128 + wc*64 + cc*4;
  const int slice = by*2 + wc;
  #pragma unroll
  for (int m = 0; m < 4; m++){
    #pragma unroll
    for (int r = 0; r < 4; r++){
      int gr = bx*256 + wr*64 + m*16 + cr + r;
      uint32_t pk = 0;
      int ip = 0;
      #pragma unroll
      for (int n = 0; n < 4; n++){
        float arg = (float)acc[m][n][r] * c1 + c2;
        arg = fminf(arg, 6.99f);
        float p = exp2f(arg);
        int pq = (int)(p + 0.5f);
        pk |= (uint32_t)pq << (n*8);
        ip += pq;
      }
      *(uint32_t*)&Cb[(size_t)gr*ldc + cb] = pk;
      float v = (float)ip;
      v += __shfl_xor(v, 1); v += __shfl_xor(v, 2);
      v += __shfl_xor(v, 4); v += __shfl_xor(v, 8);
      if (cc == 0)
        lpart[(size_t)slice * lrows + batch*Mb + gr] = v;
    }
  }
}

// ============ i8 128x128 PV GEMM, BK=128 — compile-time K ============
template<int KPER>
__global__ __launch_bounds__(256, 4) void pv128i_k(const signed char* __restrict__ A,
                                                   const signed char* __restrict__ Bm,
                                                   unsigned short* __restrict__ Cv,
                                                   int Mb,
                                                   long long sA, long long sB, long long sC,
                                                   float c1,
                                                   const float* __restrict__ linv){
  __shared__ signed char As[128*128];
  __shared__ signed char Bs[128*128];

  const int tid  = threadIdx.x;
  const int lane = tid & 63, wave = tid >> 6;
  const int wr = wave >> 1, wc = wave & 1;
  const int fr = lane & 15, kl = lane >> 4;
  const int rs = fr & 7;
  const int ldc = C_;

  const int gx = gridDim.x, gy = gridDim.y;
  const int nwg = gx * gy * gridDim.z;
  int bid = blockIdx.x + gx * (blockIdx.y + gy * blockIdx.z);
  if ((nwg & 7) == 0)
    bid = (bid & 7) * (nwg >> 3) + (bid >> 3);
  const int bx = bid % gx;
  const int tmp2 = bid / gx;
  const int by = tmp2 % gy;
  const int batch = tmp2 / gy;

  const signed char* Ab = A  + (size_t)batch*sA + (size_t)bx * 128 * KPER;
  const signed char* Bb = Bm + (size_t)batch*sB + (size_t)by * 128 * KPER;

  const int srow = tid >> 3;                                 // 0..31 (+ p*32)
  const int gcol = ((tid & 7) ^ ((tid >> 3) & 7)) * 16;
  const signed char* gA = Ab + (size_t)srow * KPER + gcol;
  const signed char* gB = Bb + (size_t)srow * KPER + gcol;
  signed char* lA = &As[srow * 128 + (tid & 7) * 16];
  signed char* lB = &Bs[srow * 128 + (tid & 7) * 16];

  i32x4 acc[4][4];
  #pragma unroll
  for (int m = 0; m < 4; m++)
    #pragma unroll
    for (int n = 0; n < 4; n++)
      acc[m][n] = (i32x4){0,0,0,0};

  constexpr int NT = KPER >> 7;

  for (int kt = 0; kt < NT; kt++){
    #pragma unroll
    for (int p = 0; p < 4; p++){
      gload16i(gA + (size_t)(p*32)*KPER + (size_t)kt*128, lA + p*4096);
      gload16i(gB + (size_t)(p*32)*KPER + (size_t)kt*128, lB + p*4096);
    }
    __syncthreads();
    i32x4 af[4][2], bf[4][2];
    #pragma unroll
    for (int m = 0; m < 4; m++)
      #pragma unroll
      for (int kk = 0; kk < 2; kk++)
        af[m][kk] = *(const i32x4*)&As[(wr*64 + m*16 + fr)*128 + (((kk*4 + kl) ^ rs) << 4)];
    #pragma unroll
    for (int n = 0; n < 4; n++)
      #pragma unroll
      for (int kk = 0; kk < 2; kk++)
        bf[n][kk] = *(const i32x4*)&Bs[(wc*64 + n*16 + fr)*128 + (((kk*4 + kl) ^ rs) << 4)];
    #pragma unroll
    for (int m = 0; m < 4; m++)
      #pragma unroll
      for (int n = 0; n < 4; n++)
        #pragma unroll
        for (int kk = 0; kk < 2; kk++)
          acc[m][n] = __builtin_amdgcn_mfma_i32_16x16x64_i8(af[m][kk], bf[n][kk], acc[m][n], 0,0,0);
    __syncthreads();
  }

  const int cr = kl * 4, cc = fr;
  unsigned short* Cb = Cv + (size_t)batch*sC;
  const int cb = by*128 + wc*64 + cc*4;
  #pragma unroll
  for (int m = 0; m < 4; m++){
    #pragma unroll
    for (int r = 0; r < 4; r++){
      int gr = bx*128 + wr*64 + m*16 + cr + r;
      float li = linv[batch*Mb + gr] * c1;
      unsigned short w0 = f2bf((float)acc[m][0][r] * li);
      unsigned short w1 = f2bf((float)acc[m][1][r] * li);
      unsigned short w2 = f2bf((float)acc[m][2][r] * li);
      unsigned short w3 = f2bf((float)acc[m][3][r] * li);
      uint2 pk;
      pk.x = (uint32_t)w0 | ((uint32_t)w1 << 16);
      pk.y = (uint32_t)w2 | ((uint32_t)w3 << 16);
      *(uint2*)&Cb[(size_t)gr*ldc + cb] = pk;
    }
  }
}

// ====== 128x128 GEMM + bias + RESIDUAL, f32 out[b][C][N] (proj fused) ======
__global__ __launch_bounds__(256, 2) void gemm_projres_k(const unsigned short* __restrict__ A,
                                                         const unsigned short* __restrict__ Bm,
                                                         const float* __restrict__ bias,
                                                         const float* __restrict__ x,
                                                         float* __restrict__ out){
  __shared__ unsigned short As[128*32];
  __shared__ unsigned short Bs[128*32];
  __shared__ float xscr[4][16*68];

  const int tid  = threadIdx.x;
  const int lane = tid & 63, wave = tid >> 6;
  const int wr = wave >> 1, wc = wave & 1;
  const int lda = C_, ldb = C_, K = C_;

  const int gx = gridDim.x, gy = gridDim.y;
  const int nwg = gx * gy;
  int bid = blockIdx.x + gx * blockIdx.y;
  if ((nwg & 7) == 0)
    bid = (bid & 7) * (nwg >> 3) + (bid >> 3);
  const int bx = bid % gx;
  const int by = bid / gx;

  const unsigned short* Ab = A  + (size_t)bx * 128 * lda;
  const unsigned short* Bb = Bm + (size_t)by * 128 * ldb;

  f32x4 acc[4][4];
  #pragma unroll
  for (int i = 0; i < 4; i++)
    #pragma unroll
    for (int j = 0; j < 4; j++)
      acc[i][j] = (f32x4){0.f, 0.f, 0.f, 0.f};

  const int ch0  = wave * 2;
  const int srow = ch0 * 16 + (lane >> 2);
  const int scol = (lane & 3) * 8;
  const unsigned short* gA0 = Ab + (size_t)srow * lda + scol;
  const unsigned short* gA1 = gA0 + (size_t)16 * lda;
  const unsigned short* gB0 = Bb + (size_t)srow * ldb + scol;
  const unsigned short* gB1 = gB0 + (size_t)16 * ldb;
  unsigned short* lA0 = &As[ch0 * 512];
  unsigned short* lA1 = &As[ch0 * 512 + 512];
  unsigned short* lB0 = &Bs[ch0 * 512];
  unsigned short* lB1 = &Bs[ch0 * 512 + 512];

  const int fr = lane & 15;
  const int fk = (lane >> 4) * 8;

  for (int k0 = 0; k0 < K; k0 += 32){
    gload16(gA0 + k0, lA0);
    gload16(gA1 + k0, lA1);
    gload16(gB0 + k0, lB0);
    gload16(gB1 + k0, lB1);
    __syncthreads();
    bf16x8 af[4], bfr[4];
    #pragma unroll
    for (int i = 0; i < 4; i++) af[i]  = *(const bf16x8*)&As[(wr*64 + i*16 + fr)*32 + fk];
    #pragma unroll
    for (int j = 0; j < 4; j++) bfr[j] = *(const bf16x8*)&Bs[(wc*64 + j*16 + fr)*32 + fk];
    #pragma unroll
    for (int i = 0; i < 4; i++)
      #pragma unroll
      for (int j = 0; j < 4; j++)
        acc[i][j] = __builtin_amdgcn_mfma_f32_16x16x32_bf16(af[i], bfr[j], acc[i][j], 0, 0, 0);
    __syncthreads();
  }

  const int cr = (lane >> 4) * 4, cc = lane & 15;
  float* scr = xscr[wave];
  const int b   = bx >> 5;
  const int n0b = (bx & 31) * 128 + wr * 64;
  const int colrd = lane >> 2;
  const int nseg  = (lane & 3) * 16;
  #pragma unroll
  for (int p = 0; p < 4; p++){
    float bv = bias[by*128 + wc*64 + p*16 + cc];
    #pragma unroll
    for (int i = 0; i < 4; i++)
      #pragma unroll
      for (int r = 0; r < 4; r++)
        scr[cc*68 + i*16 + cr + r] = acc[i][p][r] + bv;
    int col = by*128 + wc*64 + p*16 + colrd;
    size_t base = ((size_t)b*C_ + col)*N_ + n0b + nseg;
    const float* sr = &scr[colrd*68 + nseg];
    #pragma unroll
    for (int e = 0; e < 16; e += 4){
      float4 xv = *(const float4*)(x + base + e);
      float4 sv = *(const float4*)(sr + e);
      float4 ov;
      ov.x = xv.x + sv.x; ov.y = xv.y + sv.y;
      ov.z = xv.z + sv.z; ov.w = xv.w + sv.w;
      *(float4*)(out + base + e) = ov;
    }
    __builtin_amdgcn_s_barrier();
  }
}

// ---------------- reduce row-sum slices -> 1/l ----------------
__global__ __launch_bounds__(256) void lreduce_k(const float* __restrict__ lpart,
                                                 float* __restrict__ linv,
                                                 int slices, int rows){
  int r = blockIdx.x * 256 + threadIdx.x;
  if (r < rows){
    float s = 0.f;
    for (int i = 0; i < slices; i++) s += lpart[(size_t)i*rows + r];
    linv[r] = 1.f / fmaxf(s, 1.f);
  }
}

extern "C" void kernel_launch(void* const* d_in, const int* in_sizes, int n_in,
                              void* d_out, int out_size, void* d_ws, size_t ws_size,
                              hipStream_t stream){
  const float* x   = (const float*)d_in[0];
  const float* gnw = (const float*)d_in[1];
  const float* gnb = (const float*)d_in[2];
  const float* wq  = (const float*)d_in[3];
  const float* bq  = (const float*)d_in[4];
  const float* wk  = (const float*)d_in[5];
  const float* bk  = (const float*)d_in[6];
  const float* wv  = (const float*)d_in[7];
  const float* bv  = (const float*)d_in[8];
  const float* wp  = (const float*)d_in[9];
  const float* bp  = (const float*)d_in[10];
  float* out = (float*)d_out;

  char* ws = (char*)d_ws;
  const int  Mtok = B_ * N_;                      // 16384
  const size_t TSZ   = (size_t)Mtok * C_ * 2;     // 16 MB
  const size_t QKVSZ = (size_t)Mtok * 1536 * 2;   // 48 MB
  const size_t S8SZ  = (size_t)B_ * N_ * N_;      // 64 MB (i8)
  const size_t Q8SZ  = (size_t)Mtok * C_;         // 8 MB (i8)
  size_t off = 0;
  float*          stats = (float*)ws;               off += 4096;
  unsigned short* qkvw = (unsigned short*)(ws+off); off += (size_t)1536 * C_ * 2;
  unsigned short* wpb  = (unsigned short*)(ws+off); off += (size_t)C_ * C_ * 2;
  float*          bqkv = (float*)(ws+off);          off += 1536 * 4 + 2048;
  unsigned short* t    = (unsigned short*)(ws+off); off += TSZ;    // later: o
  unsigned short* qkv  = (unsigned short*)(ws+off); off += QKVSZ;
  signed char*    S8   = (signed char*)(ws+off);    off += S8SZ;
  float*          lpart = (float*)(ws+off);         off += (size_t)64 * Mtok * 4;
  float*          linv  = (float*)(ws+off);         off += (size_t)Mtok * 4;
  signed char*    q8   = (signed char*)(ws+off);    off += Q8SZ;
  signed char*    k8   = (signed char*)(ws+off);    off += Q8SZ;
  signed char*    vt8  = (signed char*)(ws+off);    off += Q8SZ;

  unsigned short* o = t;                            // t dead after QKV GEMM

  const float QS    = 6.f / 127.f;
  const float INVQS = 127.f / 6.f;
  const float qkscale = QS * QS * 0.044194173824159216f;
  const float qk_c1 = qkscale * 1.4426950408889634f;     // log2-space scale
  const float qk_c2 = -0.22478961f;                      // log2(127/e^5)

  prep_k<<<1025, 256, 0, stream>>>(wq, wk, wv, wp, bq, bk, bv, qkvw, wpb, bqkv);

  gn_stats_k<<<B_ * G_, 256, 0, stream>>>(x, stats);
  gn_apply_k<<<dim3(N_/64, C_/64, B_), 256, 0, stream>>>(x, stats, gnw, gnb, t);

  // QKV: mode 3 — by<4 writes packed i8 q8/k8 (pi-permuted channels), by>=4 bf16 v
  gemm256_k<<<dim3(Mtok/256, 1536/256, 1), 512, 0, stream>>>(
      t, qkvw, qkv, C_, C_, 1536, C_, 1, Mtok, 0,0,0,0, bqkv, 1.f, 3, q8, k8, INVQS);

  // v -> vt8[b][d][pi(n)] i8
  transpose_q8_k<<<dim3(N_/64, C_/64, B_), 256, 0, stream>>>(qkv + 1024, vt8, INVQS);

  const long long sQ8 = (long long)N_ * C_;
  const long long sNN = (long long)N_ * N_;
  const long long sNC = (long long)N_ * C_;

  // QK (i8, 256x128, KPER=512): S8 packed; row sums -> lpart. Mb = N_ per-batch rows
  qk256i_k<512><<<dim3(N_/256, N_/128, B_), 512, 0, stream>>>(
      q8, k8, S8, N_, sQ8, sQ8, sNN, qk_c1, qk_c2, lpart, Mtok);

  lreduce_k<<<Mtok/256, 256, 0, stream>>>(lpart, linv, 64, Mtok);

  // PV (i8, 128^2, KPER=4096): o = (S8 x Vt8) * QS * linv[row]. Mb = N_
  pv128i_k<4096><<<dim3(N_/128, C_/128, B_), 256, 0, stream>>>(
      S8, vt8, o, N_, sNN, sQ8, sNC, QS, linv);

  // out = x + o wp^T + bp   (residual fused into proj epilogue, f32 out)
  gemm_projres_k<<<dim3(Mtok/128, C_/128), 256, 0, stream>>>(o, wpb, bp, x, out);
}